// Round 2
// baseline (1124.957 us; speedup 1.0000x reference)
//
#include <hip/hip_runtime.h>

// VQ-VAE vector quantizer, MI355X (gfx950)
// B=16, C=256, H=W=32 -> N=16384 pixels; K=8192 codes.
// Key insight (round 1 post-mortem): the harness's np reference computes
// distances = z_sq - 2*cross + e_sq in FP32. Near-tie argmin decisions
// (~400 of 16384 pixels) are decided by the reference's own fp32 rounding
// lattice (ulp(z_sq)~3e-5 vs top-2 gaps ~Exp(3.6e-4)). So we must
// REPLICATE the fp32 pipeline: bit-exact numpy-pairwise z_sq and e_sq,
// cross to ~1e-9 via two-limb fp16 MFMA split, and the same elementwise
// fp32 rounding structure fl(fl(Z - 2c) + es).

typedef _Float16 f16;
typedef __attribute__((ext_vector_type(8))) _Float16 f16x8;
typedef __attribute__((ext_vector_type(4))) _Float16 f16x4;
typedef __attribute__((ext_vector_type(4))) float f32x4;

#define NPIX   16384      // B*H*W
#define CDIM   256
#define KCODE  8192

// ---------------- K0: z (B,C,H,W) -> zhi/zlo [n][c] fp16, pixel-major ----------------
__global__ void k_zsplit(const float* __restrict__ z, f16* __restrict__ zhi,
                         f16* __restrict__ zlo) {
  int b  = blockIdx.x >> 4;      // 16
  int pt = blockIdx.x & 15;      // 16 tiles of 64 pixels
  int t  = threadIdx.x;
  int pl = t & 63;
  int g  = t >> 6;               // 4 c-groups of 64
  int p0 = pt * 64;
  size_t n = (size_t)b * 1024 + p0 + pl;
  const float* src = z + ((size_t)b * CDIM) * 1024 + p0 + pl;   // + c*1024
  for (int cg = 0; cg < 8; ++cg) {
    int c0 = g * 64 + cg * 8;
    f16x8 h8, l8;
#pragma unroll
    for (int j = 0; j < 8; ++j) {
      float v = src[(size_t)(c0 + j) * 1024];     // coalesced along pl
      f16 h = (f16)v;
      h8[j] = h;
      l8[j] = (f16)((v - (float)h) * 4096.0f);    // scaled low limb, normal range
    }
    *(f16x8*)(zhi + n * CDIM + c0) = h8;
    *(f16x8*)(zlo + n * CDIM + c0) = l8;
  }
}

// ---------------- K0b: z_sq, bit-exact replication of numpy pairwise fp32 sum ----------------
// np.sum over contiguous len-256 fp32: split 128+128; each 128-block: 8 stride-8
// accumulators r[j] (r[j] = a[j]+a[j+8]+...+a[j+120], sequential), combined as
// ((r0+r1)+(r2+r3))+((r4+r5)+(r6+r7)); then half0+half1. a[c] = fl(z_c * z_c).
__global__ void k_zsq(const float* __restrict__ z, float* __restrict__ zsq) {
#pragma clang fp contract(off)
  int n = blockIdx.x * 256 + threadIdx.x;
  int b = n >> 10, p = n & 1023;
  const float* src = z + (size_t)b * CDIM * 1024 + p;
  float half[2];
  for (int m = 0; m < 2; ++m) {
    float r[8];
#pragma unroll
    for (int j = 0; j < 8; ++j) r[j] = 0.0f;
    for (int i = 0; i < 16; ++i) {
#pragma unroll
      for (int j = 0; j < 8; ++j) {
        float v = src[(size_t)(m * 128 + i * 8 + j) * 1024];   // coalesced across lanes
        r[j] = r[j] + v * v;                                   // mul then add (no fma)
      }
    }
    half[m] = ((r[0] + r[1]) + (r[2] + r[3])) + ((r[4] + r[5]) + (r[6] + r[7]));
  }
  zsq[n] = half[0] + half[1];
}

// ---------------- K1: codebook -> chi/clo fp16 (scaled by 8192) ----------------
__global__ void k_cbsplit(const float* __restrict__ cb, f16* __restrict__ chi,
                          f16* __restrict__ clo) {
  int row  = blockIdx.x * 4 + (threadIdx.x >> 6);   // one wave per row
  int lane = threadIdx.x & 63;
  const float4 v = *(const float4*)(cb + (size_t)row * CDIM + lane * 4);
  float e0 = v.x * 8192.0f, e1 = v.y * 8192.0f, e2 = v.z * 8192.0f, e3 = v.w * 8192.0f;
  f16 h0 = (f16)e0, h1 = (f16)e1, h2 = (f16)e2, h3 = (f16)e3;
  f16x4 hi4 = {h0, h1, h2, h3};
  f16x4 lo4 = {(f16)((e0 - (float)h0) * 4096.0f), (f16)((e1 - (float)h1) * 4096.0f),
               (f16)((e2 - (float)h2) * 4096.0f), (f16)((e3 - (float)h3) * 4096.0f)};
  *(f16x4*)(chi + (size_t)row * CDIM + lane * 4) = hi4;
  *(f16x4*)(clo + (size_t)row * CDIM + lane * 4) = lo4;
}

// ---------------- K1b: e_sq, bit-exact numpy pairwise (thread per row) ----------------
__global__ void k_esq(const float* __restrict__ cb, float* __restrict__ esq) {
#pragma clang fp contract(off)
  int row = blockIdx.x * 256 + threadIdx.x;
  const float* src = cb + (size_t)row * CDIM;
  float half[2];
  for (int m = 0; m < 2; ++m) {
    float r[8];
#pragma unroll
    for (int j = 0; j < 8; ++j) r[j] = 0.0f;
    for (int i = 0; i < 16; ++i) {
      float4 v0 = *(const float4*)(src + m * 128 + i * 8);
      float4 v1 = *(const float4*)(src + m * 128 + i * 8 + 4);
      r[0] = r[0] + v0.x * v0.x;  r[1] = r[1] + v0.y * v0.y;
      r[2] = r[2] + v0.z * v0.z;  r[3] = r[3] + v0.w * v0.w;
      r[4] = r[4] + v1.x * v1.x;  r[5] = r[5] + v1.y * v1.y;
      r[6] = r[6] + v1.z * v1.z;  r[7] = r[7] + v1.w * v1.w;
    }
    half[m] = ((r[0] + r[1]) + (r[2] + r[3])) + ((r[4] + r[5]) + (r[6] + r[7]));
  }
  esq[row] = half[0] + half[1];
}

// ---------------- K2: fused score GEMM + argmin ----------------
// grid 2048 = 256 px-tiles x 8 k-slices. block 256 thr (4 waves).
// A-tile 64px x 256c hi+lo in 64KB LDS (16B xor swizzle). wave-tile 64px x 64codes/iter.
__launch_bounds__(256, 2)
__global__ void k_score(const f16* __restrict__ zhi, const f16* __restrict__ zlo,
                        const f16* __restrict__ chi, const f16* __restrict__ clo,
                        const float* __restrict__ esq, const float* __restrict__ zsq,
                        unsigned long long* __restrict__ best) {
  extern __shared__ char smem[];
  f16* sAh = (f16*)smem;               // 32 KB
  f16* sAl = (f16*)(smem + 32768);     // 32 KB
  int bid = blockIdx.x;
  int kslice = bid & 7;
  int ptile  = bid >> 3;
  int t = threadIdx.x;
  int wave = t >> 6, lane = t & 63;
  int quad = lane >> 4, l15 = lane & 15;
  int p0 = ptile * 64;

  // ---- stage A-tile (hi & lo), xor-swizzled at 16B granularity ----
  {
    int r = t >> 2, seg = t & 3;
    const uint4* gh = (const uint4*)zhi + ((size_t)(p0 + r)) * 32;
    const uint4* gl = (const uint4*)zlo + ((size_t)(p0 + r)) * 32;
    uint4* sh = (uint4*)sAh + r * 32;
    uint4* sl = (uint4*)sAl + r * 32;
#pragma unroll
    for (int j = 0; j < 8; ++j) {
      int blk = seg * 8 + j;
      int sb = blk ^ (r & 7);
      sh[sb] = gh[blk];
      sl[sb] = gl[blk];
    }
  }

  // Z for my 16 pixel rows (C/D layout: row = quad*4 + reg)
  float Zr[16];
#pragma unroll
  for (int rt = 0; rt < 4; ++rt)
#pragma unroll
    for (int rr = 0; rr < 4; ++rr)
      Zr[rt * 4 + rr] = zsq[p0 + rt * 16 + quad * 4 + rr];

  __syncthreads();

  float bs[16];
  int   bi[16];
#pragma unroll
  for (int j = 0; j < 16; ++j) { bs[j] = 3.0e38f; bi[j] = 0; }

  const f32x4 vzero = {0.0f, 0.0f, 0.0f, 0.0f};

  for (int iter = 0; iter < 4; ++iter) {
    int kbase = kslice * 1024 + iter * 256 + wave * 64;
    f32x4 hh[4][4], mx[4][4];
#pragma unroll
    for (int rt = 0; rt < 4; ++rt)
#pragma unroll
      for (int kt = 0; kt < 4; ++kt) { hh[rt][kt] = vzero; mx[rt][kt] = vzero; }

#pragma unroll
    for (int cs = 0; cs < 8; ++cs) {
      int c0 = cs * 32 + quad * 8;
      f16x8 bh[4], bl[4], ah[4], al[4];
#pragma unroll
      for (int kt = 0; kt < 4; ++kt) {
        size_t off = ((size_t)(kbase + kt * 16 + l15)) * CDIM + c0;
        bh[kt] = *(const f16x8*)(chi + off);
        bl[kt] = *(const f16x8*)(clo + off);
      }
#pragma unroll
      for (int rt = 0; rt < 4; ++rt) {
        int px = rt * 16 + l15;
        int sb = (cs * 4 + quad) ^ (px & 7);
        int eo = px * 256 + sb * 8;          // f16 units
        ah[rt] = *(const f16x8*)(sAh + eo);
        al[rt] = *(const f16x8*)(sAl + eo);
      }
#pragma unroll
      for (int rt = 0; rt < 4; ++rt)
#pragma unroll
        for (int kt = 0; kt < 4; ++kt) {
          hh[rt][kt] = __builtin_amdgcn_mfma_f32_16x16x32_f16(ah[rt], bh[kt], hh[rt][kt], 0, 0, 0);
          mx[rt][kt] = __builtin_amdgcn_mfma_f32_16x16x32_f16(ah[rt], bl[kt], mx[rt][kt], 0, 0, 0);
          mx[rt][kt] = __builtin_amdgcn_mfma_f32_16x16x32_f16(al[rt], bh[kt], mx[rt][kt], 0, 0, 0);
        }
    }

    // epilogue: replicate ref's fp32 rounding: d = fl(fl(Z - 2c) + es)
    // 2c = hh/4096 (exact scale) + mx/2^24 (one fmaf rounding)
#pragma unroll
    for (int kt = 0; kt < 4; ++kt) {
      int k = kbase + kt * 16 + l15;
      float es = esq[k];
#pragma unroll
      for (int rt = 0; rt < 4; ++rt)
#pragma unroll
        for (int rr = 0; rr < 4; ++rr) {
          float v = hh[rt][kt][rr] * 2.44140625e-4f;                       // /4096, exact
          float w = fmaf(mx[rt][kt][rr], 5.9604644775390625e-8f, v);       // ~2*cross
          float d = (Zr[rt * 4 + rr] - w) + es;                            // two fp32 roundings
          int j = rt * 4 + rr;
          if (d < bs[j]) { bs[j] = d; bi[j] = k; }
        }
    }
  }

  // ---- reduce across the 16 lanes of each quad, then across waves ----
  __syncthreads();                          // A-tile dead; reuse LDS
  unsigned long long* red = (unsigned long long*)smem;   // 4 waves x 64 rows
#pragma unroll
  for (int j = 0; j < 16; ++j) {
    float s = bs[j]; int i_ = bi[j];
#pragma unroll
    for (int m = 1; m <= 8; m <<= 1) {
      float s2 = __shfl_xor(s, m);
      int   i2 = __shfl_xor(i_, m);
      if (s2 < s || (s2 == s && i2 < i_)) { s = s2; i_ = i2; }
    }
    if (l15 == 0) {
      int row = ((j >> 2) << 4) + (quad << 2) + (j & 3);   // rt*16 + quad*4 + rr
      unsigned u = __float_as_uint(s);
      u = (u & 0x80000000u) ? ~u : (u | 0x80000000u);      // order-preserving map
      red[wave * 64 + row] = ((unsigned long long)u << 32) | (unsigned)i_;
    }
  }
  __syncthreads();
  if (wave == 0) {
    unsigned long long m0 = red[lane];
    unsigned long long m1 = red[64 + lane];
    unsigned long long m2 = red[128 + lane];
    unsigned long long m3 = red[192 + lane];
    unsigned long long a = m0 < m1 ? m0 : m1;
    unsigned long long c = m2 < m3 ? m2 : m3;
    a = a < c ? a : c;
    atomicMin(&best[p0 + lane], a);
  }
}

// ---------------- K3: gather quantized, write codes, accumulate loss ----------------
__global__ void k_gather(const float* __restrict__ z, const float* __restrict__ cb,
                         const unsigned long long* __restrict__ best,
                         float* __restrict__ out_codes, float* __restrict__ out_q,
                         float* __restrict__ lossac) {
  int b  = blockIdx.x >> 4;
  int cg = blockIdx.x & 15;
  int t  = threadIdx.x;
  int idx[4];
#pragma unroll
  for (int pi = 0; pi < 4; ++pi) {
    int p = t + pi * 256;
    unsigned long long pk = best[b * 1024 + p];
    idx[pi] = (int)(unsigned)(pk & 0xffffffffu);
    if (cg == 0) out_codes[b * 1024 + p] = (float)idx[pi];
  }
  float lsum = 0.0f;
#pragma unroll
  for (int ci = 0; ci < 16; ++ci) {
    int c = cg * 16 + ci;
#pragma unroll
    for (int pi = 0; pi < 4; ++pi) {
      int p = t + pi * 256;
      float q  = cb[(size_t)idx[pi] * CDIM + c];
      size_t o = ((size_t)(b * CDIM + c)) * 1024 + p;
      float zv = z[o];
      float d  = q - zv;
      out_q[o] = zv + d;                 // straight-through: same op order as reference
      lsum = fmaf(d, d, lsum);
    }
  }
#pragma unroll
  for (int m = 32; m >= 1; m >>= 1) lsum += __shfl_xor(lsum, m);
  __shared__ float wsum[4];
  if ((t & 63) == 0) wsum[t >> 6] = lsum;
  __syncthreads();
  if (t == 0) atomicAdd(lossac, wsum[0] + wsum[1] + wsum[2] + wsum[3]);
}

// ---------------- K4: finalize loss scalar ----------------
__global__ void k_final(const float* __restrict__ lossac, float* __restrict__ out_loss) {
  if (threadIdx.x == 0) out_loss[0] = lossac[0] * (1.25f / 4194304.0f);
}

extern "C" void kernel_launch(void* const* d_in, const int* in_sizes, int n_in,
                              void* d_out, int out_size, void* d_ws, size_t ws_size,
                              hipStream_t stream) {
  (void)in_sizes; (void)n_in; (void)out_size; (void)ws_size;
  const float* z  = (const float*)d_in[0];
  const float* cb = (const float*)d_in[1];
  float* outf = (float*)d_out;

  char* ws = (char*)d_ws;
  f16*   chi  = (f16*)ws;                                   // 4 MB
  f16*   clo  = (f16*)(ws + (4 << 20));                     // 4 MB
  float* esq  = (float*)(ws + (8 << 20));                   // 32 KB
  unsigned long long* best = (unsigned long long*)(ws + (8 << 20) + 32768);  // 128 KB
  float* lossac = (float*)(ws + (8 << 20) + 32768 + 131072);                 // 4 B
  float* zsq    = (float*)(ws + (8 << 20) + 32768 + 131072 + 256);           // 64 KB

  // scratch inside d_out's quantized region (overwritten by k_gather afterwards)
  f16* zhi = (f16*)(outf + 16384);                          // 8 MB
  f16* zlo = zhi + (size_t)NPIX * CDIM;                     // 8 MB

  hipMemsetAsync(best, 0xFF, (size_t)NPIX * 8, stream);
  hipMemsetAsync(lossac, 0, 4, stream);

  k_zsplit <<<256,  256, 0,     stream>>>(z, zhi, zlo);
  k_zsq    <<<64,   256, 0,     stream>>>(z, zsq);
  k_cbsplit<<<2048, 256, 0,     stream>>>(cb, chi, clo);
  k_esq    <<<32,   256, 0,     stream>>>(cb, esq);
  k_score  <<<2048, 256, 65536, stream>>>(zhi, zlo, chi, clo, esq, zsq, best);
  k_gather <<<256,  256, 0,     stream>>>(z, cb, best, outf, outf + 16384, lossac);
  k_final  <<<1,    64,  0,     stream>>>(lossac, outf + 16384 + (size_t)NPIX * CDIM);
}

// Round 3
// 886.622 us; speedup vs baseline: 1.2688x; 1.2688x over previous
//
#include <hip/hip_runtime.h>

// VQ-VAE vector quantizer, MI355X (gfx950)
// B=16, C=256, H=W=32 -> N=16384 pixels; K=8192 codes.
// R2 post-mortem: k_score spilled accumulators (WRITE_SIZE 1 GB/dispatch) --
// 64x64 wave tile needs ~260 regs > 256 budget at 2 waves/SIMD. R3: 64x32
// wave tile (kt=2, 8 iters) -> ~190 regs, no spill, L2-resident B-slice.

typedef _Float16 f16;
typedef __attribute__((ext_vector_type(8))) _Float16 f16x8;
typedef __attribute__((ext_vector_type(4))) _Float16 f16x4;
typedef __attribute__((ext_vector_type(4))) float f32x4;

#define NPIX   16384      // B*H*W
#define CDIM   256
#define KCODE  8192

// ---------------- K0: z (B,C,H,W) -> zhi/zlo [n][c] fp16, pixel-major ----------------
__global__ void k_zsplit(const float* __restrict__ z, f16* __restrict__ zhi,
                         f16* __restrict__ zlo) {
  int b  = blockIdx.x >> 4;      // 16
  int pt = blockIdx.x & 15;      // 16 tiles of 64 pixels
  int t  = threadIdx.x;
  int pl = t & 63;
  int g  = t >> 6;               // 4 c-groups of 64
  int p0 = pt * 64;
  size_t n = (size_t)b * 1024 + p0 + pl;
  const float* src = z + ((size_t)b * CDIM) * 1024 + p0 + pl;   // + c*1024
  for (int cg = 0; cg < 8; ++cg) {
    int c0 = g * 64 + cg * 8;
    f16x8 h8, l8;
#pragma unroll
    for (int j = 0; j < 8; ++j) {
      float v = src[(size_t)(c0 + j) * 1024];     // coalesced along pl
      f16 h = (f16)v;
      h8[j] = h;
      l8[j] = (f16)((v - (float)h) * 4096.0f);    // scaled low limb, normal range
    }
    *(f16x8*)(zhi + n * CDIM + c0) = h8;
    *(f16x8*)(zlo + n * CDIM + c0) = l8;
  }
}

// ---------------- K0b: z_sq, bit-exact replication of numpy pairwise fp32 sum ----------------
__global__ void k_zsq(const float* __restrict__ z, float* __restrict__ zsq) {
#pragma clang fp contract(off)
  int n = blockIdx.x * 256 + threadIdx.x;
  int b = n >> 10, p = n & 1023;
  const float* src = z + (size_t)b * CDIM * 1024 + p;
  float half[2];
  for (int m = 0; m < 2; ++m) {
    float r[8];
#pragma unroll
    for (int j = 0; j < 8; ++j) r[j] = 0.0f;
    for (int i = 0; i < 16; ++i) {
#pragma unroll
      for (int j = 0; j < 8; ++j) {
        float v = src[(size_t)(m * 128 + i * 8 + j) * 1024];   // coalesced across lanes
        r[j] = r[j] + v * v;                                   // mul then add (no fma)
      }
    }
    half[m] = ((r[0] + r[1]) + (r[2] + r[3])) + ((r[4] + r[5]) + (r[6] + r[7]));
  }
  zsq[n] = half[0] + half[1];
}

// ---------------- K1: codebook -> chi/clo fp16 (scaled by 8192) ----------------
__global__ void k_cbsplit(const float* __restrict__ cb, f16* __restrict__ chi,
                          f16* __restrict__ clo) {
  int row  = blockIdx.x * 4 + (threadIdx.x >> 6);   // one wave per row
  int lane = threadIdx.x & 63;
  const float4 v = *(const float4*)(cb + (size_t)row * CDIM + lane * 4);
  float e0 = v.x * 8192.0f, e1 = v.y * 8192.0f, e2 = v.z * 8192.0f, e3 = v.w * 8192.0f;
  f16 h0 = (f16)e0, h1 = (f16)e1, h2 = (f16)e2, h3 = (f16)e3;
  f16x4 hi4 = {h0, h1, h2, h3};
  f16x4 lo4 = {(f16)((e0 - (float)h0) * 4096.0f), (f16)((e1 - (float)h1) * 4096.0f),
               (f16)((e2 - (float)h2) * 4096.0f), (f16)((e3 - (float)h3) * 4096.0f)};
  *(f16x4*)(chi + (size_t)row * CDIM + lane * 4) = hi4;
  *(f16x4*)(clo + (size_t)row * CDIM + lane * 4) = lo4;
}

// ---------------- K1b: e_sq, bit-exact numpy pairwise (thread per row) ----------------
__global__ void k_esq(const float* __restrict__ cb, float* __restrict__ esq) {
#pragma clang fp contract(off)
  int row = blockIdx.x * 256 + threadIdx.x;
  const float* src = cb + (size_t)row * CDIM;
  float half[2];
  for (int m = 0; m < 2; ++m) {
    float r[8];
#pragma unroll
    for (int j = 0; j < 8; ++j) r[j] = 0.0f;
    for (int i = 0; i < 16; ++i) {
      float4 v0 = *(const float4*)(src + m * 128 + i * 8);
      float4 v1 = *(const float4*)(src + m * 128 + i * 8 + 4);
      r[0] = r[0] + v0.x * v0.x;  r[1] = r[1] + v0.y * v0.y;
      r[2] = r[2] + v0.z * v0.z;  r[3] = r[3] + v0.w * v0.w;
      r[4] = r[4] + v1.x * v1.x;  r[5] = r[5] + v1.y * v1.y;
      r[6] = r[6] + v1.z * v1.z;  r[7] = r[7] + v1.w * v1.w;
    }
    half[m] = ((r[0] + r[1]) + (r[2] + r[3])) + ((r[4] + r[5]) + (r[6] + r[7]));
  }
  esq[row] = half[0] + half[1];
}

// ---------------- K2: fused score GEMM + argmin ----------------
// grid 2048 = 256 px-tiles x 8 k-slices (kslice = bid&7 aligns with round-robin
// XCD dispatch -> each XCD's 1MB codebook slice stays L2-resident).
// block 256 thr (4 waves), 2 blocks/CU. A-tile 64px x 256c hi+lo in 64KB LDS
// (16B xor swizzle). Wave tile per iter: 64px x 32 codes; 8 iters.
// Register budget (the R2 spill fix): acc 16xf32x4=64 + frags 48 + bs/bi 32
// + Zr 16 + misc ~= 190 < 256 at 2 waves/SIMD.
__launch_bounds__(256, 2)
__global__ void k_score(const f16* __restrict__ zhi, const f16* __restrict__ zlo,
                        const f16* __restrict__ chi, const f16* __restrict__ clo,
                        const float* __restrict__ esq, const float* __restrict__ zsq,
                        unsigned long long* __restrict__ best) {
  extern __shared__ char smem[];
  f16* sAh = (f16*)smem;               // 32 KB
  f16* sAl = (f16*)(smem + 32768);     // 32 KB
  int bid = blockIdx.x;
  int kslice = bid & 7;
  int ptile  = bid >> 3;
  int t = threadIdx.x;
  int wave = t >> 6, lane = t & 63;
  int quad = lane >> 4, l15 = lane & 15;
  int p0 = ptile * 64;

  // ---- stage A-tile (hi & lo), xor-swizzled at 16B granularity ----
  {
    int r = t >> 2, seg = t & 3;
    const uint4* gh = (const uint4*)zhi + ((size_t)(p0 + r)) * 32;
    const uint4* gl = (const uint4*)zlo + ((size_t)(p0 + r)) * 32;
    uint4* sh = (uint4*)sAh + r * 32;
    uint4* sl = (uint4*)sAl + r * 32;
#pragma unroll
    for (int j = 0; j < 8; ++j) {
      int blk = seg * 8 + j;
      int sb = blk ^ (r & 7);
      sh[sb] = gh[blk];
      sl[sb] = gl[blk];
    }
  }

  // Z for my 16 pixel rows (C/D layout: row = quad*4 + reg)
  float Zr[16];
#pragma unroll
  for (int rt = 0; rt < 4; ++rt)
#pragma unroll
    for (int rr = 0; rr < 4; ++rr)
      Zr[rt * 4 + rr] = zsq[p0 + rt * 16 + quad * 4 + rr];

  __syncthreads();

  float bs[16];
  int   bi[16];
#pragma unroll
  for (int j = 0; j < 16; ++j) { bs[j] = 3.0e38f; bi[j] = 0; }

  const f32x4 vzero = {0.0f, 0.0f, 0.0f, 0.0f};

#pragma unroll 1
  for (int iter = 0; iter < 8; ++iter) {
    int kbase = kslice * 1024 + iter * 128 + wave * 32;
    f32x4 hh[4][2], mx[4][2];
#pragma unroll
    for (int rt = 0; rt < 4; ++rt)
#pragma unroll
      for (int kt = 0; kt < 2; ++kt) { hh[rt][kt] = vzero; mx[rt][kt] = vzero; }

#pragma unroll
    for (int cs = 0; cs < 8; ++cs) {
      int c0 = cs * 32 + quad * 8;
      f16x8 bh[2], bl[2], ah[4], al[4];
#pragma unroll
      for (int kt = 0; kt < 2; ++kt) {
        size_t off = ((size_t)(kbase + kt * 16 + l15)) * CDIM + c0;
        bh[kt] = *(const f16x8*)(chi + off);
        bl[kt] = *(const f16x8*)(clo + off);
      }
#pragma unroll
      for (int rt = 0; rt < 4; ++rt) {
        int px = rt * 16 + l15;
        int sb = (cs * 4 + quad) ^ (px & 7);
        int eo = px * 256 + sb * 8;          // f16 units
        ah[rt] = *(const f16x8*)(sAh + eo);
        al[rt] = *(const f16x8*)(sAl + eo);
      }
#pragma unroll
      for (int rt = 0; rt < 4; ++rt)
#pragma unroll
        for (int kt = 0; kt < 2; ++kt) {
          hh[rt][kt] = __builtin_amdgcn_mfma_f32_16x16x32_f16(ah[rt], bh[kt], hh[rt][kt], 0, 0, 0);
          mx[rt][kt] = __builtin_amdgcn_mfma_f32_16x16x32_f16(ah[rt], bl[kt], mx[rt][kt], 0, 0, 0);
          mx[rt][kt] = __builtin_amdgcn_mfma_f32_16x16x32_f16(al[rt], bh[kt], mx[rt][kt], 0, 0, 0);
        }
    }

    // epilogue: replicate ref's fp32 rounding: d = fl(fl(Z - 2c) + es)
    // 2c = hh/4096 (exact scale) + mx/2^24 (one fmaf rounding)
#pragma unroll
    for (int kt = 0; kt < 2; ++kt) {
      int k = kbase + kt * 16 + l15;
      float es = esq[k];
#pragma unroll
      for (int rt = 0; rt < 4; ++rt)
#pragma unroll
        for (int rr = 0; rr < 4; ++rr) {
          float v = hh[rt][kt][rr] * 2.44140625e-4f;                       // /4096, exact
          float w = fmaf(mx[rt][kt][rr], 5.9604644775390625e-8f, v);       // ~2*cross
          float d = (Zr[rt * 4 + rr] - w) + es;                            // two fp32 roundings
          int j = rt * 4 + rr;
          if (d < bs[j]) { bs[j] = d; bi[j] = k; }
        }
    }
  }

  // ---- reduce across the 16 lanes of each quad, then across waves ----
  __syncthreads();                          // A-tile dead; reuse LDS
  unsigned long long* red = (unsigned long long*)smem;   // 4 waves x 64 rows
#pragma unroll
  for (int j = 0; j < 16; ++j) {
    float s = bs[j]; int i_ = bi[j];
#pragma unroll
    for (int m = 1; m <= 8; m <<= 1) {
      float s2 = __shfl_xor(s, m);
      int   i2 = __shfl_xor(i_, m);
      if (s2 < s || (s2 == s && i2 < i_)) { s = s2; i_ = i2; }
    }
    if (l15 == 0) {
      int row = ((j >> 2) << 4) + (quad << 2) + (j & 3);   // rt*16 + quad*4 + rr
      unsigned u = __float_as_uint(s);
      u = (u & 0x80000000u) ? ~u : (u | 0x80000000u);      // order-preserving map
      red[wave * 64 + row] = ((unsigned long long)u << 32) | (unsigned)i_;
    }
  }
  __syncthreads();
  if (wave == 0) {
    unsigned long long m0 = red[lane];
    unsigned long long m1 = red[64 + lane];
    unsigned long long m2 = red[128 + lane];
    unsigned long long m3 = red[192 + lane];
    unsigned long long a = m0 < m1 ? m0 : m1;
    unsigned long long c = m2 < m3 ? m2 : m3;
    a = a < c ? a : c;
    atomicMin(&best[p0 + lane], a);
  }
}

// ---------------- K3: gather quantized, write codes, accumulate loss ----------------
__global__ void k_gather(const float* __restrict__ z, const float* __restrict__ cb,
                         const unsigned long long* __restrict__ best,
                         float* __restrict__ out_codes, float* __restrict__ out_q,
                         float* __restrict__ lossac) {
  int b  = blockIdx.x >> 4;
  int cg = blockIdx.x & 15;
  int t  = threadIdx.x;
  int idx[4];
#pragma unroll
  for (int pi = 0; pi < 4; ++pi) {
    int p = t + pi * 256;
    unsigned long long pk = best[b * 1024 + p];
    idx[pi] = (int)(unsigned)(pk & 0xffffffffu);
    if (cg == 0) out_codes[b * 1024 + p] = (float)idx[pi];
  }
  float lsum = 0.0f;
#pragma unroll
  for (int ci = 0; ci < 16; ++ci) {
    int c = cg * 16 + ci;
#pragma unroll
    for (int pi = 0; pi < 4; ++pi) {
      int p = t + pi * 256;
      float q  = cb[(size_t)idx[pi] * CDIM + c];
      size_t o = ((size_t)(b * CDIM + c)) * 1024 + p;
      float zv = z[o];
      float d  = q - zv;
      out_q[o] = zv + d;                 // straight-through: same op order as reference
      lsum = fmaf(d, d, lsum);
    }
  }
#pragma unroll
  for (int m = 32; m >= 1; m >>= 1) lsum += __shfl_xor(lsum, m);
  __shared__ float wsum[4];
  if ((t & 63) == 0) wsum[t >> 6] = lsum;
  __syncthreads();
  if (t == 0) atomicAdd(lossac, wsum[0] + wsum[1] + wsum[2] + wsum[3]);
}

// ---------------- K4: finalize loss scalar ----------------
__global__ void k_final(const float* __restrict__ lossac, float* __restrict__ out_loss) {
  if (threadIdx.x == 0) out_loss[0] = lossac[0] * (1.25f / 4194304.0f);
}

extern "C" void kernel_launch(void* const* d_in, const int* in_sizes, int n_in,
                              void* d_out, int out_size, void* d_ws, size_t ws_size,
                              hipStream_t stream) {
  (void)in_sizes; (void)n_in; (void)out_size; (void)ws_size;
  const float* z  = (const float*)d_in[0];
  const float* cb = (const float*)d_in[1];
  float* outf = (float*)d_out;

  char* ws = (char*)d_ws;
  f16*   chi  = (f16*)ws;                                   // 4 MB
  f16*   clo  = (f16*)(ws + (4 << 20));                     // 4 MB
  float* esq  = (float*)(ws + (8 << 20));                   // 32 KB
  unsigned long long* best = (unsigned long long*)(ws + (8 << 20) + 32768);  // 128 KB
  float* lossac = (float*)(ws + (8 << 20) + 32768 + 131072);                 // 4 B
  float* zsq    = (float*)(ws + (8 << 20) + 32768 + 131072 + 256);           // 64 KB

  // scratch inside d_out's quantized region (overwritten by k_gather afterwards)
  f16* zhi = (f16*)(outf + 16384);                          // 8 MB
  f16* zlo = zhi + (size_t)NPIX * CDIM;                     // 8 MB

  hipMemsetAsync(best, 0xFF, (size_t)NPIX * 8, stream);
  hipMemsetAsync(lossac, 0, 4, stream);

  k_zsplit <<<256,  256, 0,     stream>>>(z, zhi, zlo);
  k_zsq    <<<64,   256, 0,     stream>>>(z, zsq);
  k_cbsplit<<<2048, 256, 0,     stream>>>(cb, chi, clo);
  k_esq    <<<32,   256, 0,     stream>>>(cb, esq);
  k_score  <<<2048, 256, 65536, stream>>>(zhi, zlo, chi, clo, esq, zsq, best);
  k_gather <<<256,  256, 0,     stream>>>(z, cb, best, outf, outf + 16384, lossac);
  k_final  <<<1,    64,  0,     stream>>>(lossac, outf + 16384 + (size_t)NPIX * CDIM);
}

// Round 4
// 545.712 us; speedup vs baseline: 2.0614x; 1.6247x over previous
//
#include <hip/hip_runtime.h>

// VQ-VAE vector quantizer, MI355X (gfx950)
// B=16, C=256, H=W=32 -> N=16384 pixels; K=8192 codes.
// R3 post-mortem: (1) __launch_bounds__(256,2) let the compiler target 4
// waves/EU -> 128 unified VGPR cap -> ~1.1KB/thread scratch spill
// (WRITE_SIZE 573 MB). LDS caps occupancy at 2 blocks/CU anyway, so use
// (256,1) and let the allocator take ~190 regs. (2) bid&7 is NOT the XCD
// mapping on this machine (FETCH 1.74 GB = 82% B-miss): claim kslice from
// the real XCD id (s_getreg HW_REG_XCC_ID) + per-slice ticket counters so
// each XCD's 1 MB codebook slice is L2-resident.

typedef _Float16 f16;
typedef __attribute__((ext_vector_type(8))) _Float16 f16x8;
typedef __attribute__((ext_vector_type(4))) _Float16 f16x4;
typedef __attribute__((ext_vector_type(4))) float f32x4;

#define NPIX   16384      // B*H*W
#define CDIM   256
#define KCODE  8192

// ---------------- K0: z (B,C,H,W) -> zhi/zlo [n][c] fp16, pixel-major ----------------
__global__ void k_zsplit(const float* __restrict__ z, f16* __restrict__ zhi,
                         f16* __restrict__ zlo) {
  int b  = blockIdx.x >> 4;      // 16
  int pt = blockIdx.x & 15;      // 16 tiles of 64 pixels
  int t  = threadIdx.x;
  int pl = t & 63;
  int g  = t >> 6;               // 4 c-groups of 64
  int p0 = pt * 64;
  size_t n = (size_t)b * 1024 + p0 + pl;
  const float* src = z + ((size_t)b * CDIM) * 1024 + p0 + pl;   // + c*1024
  for (int cg = 0; cg < 8; ++cg) {
    int c0 = g * 64 + cg * 8;
    f16x8 h8, l8;
#pragma unroll
    for (int j = 0; j < 8; ++j) {
      float v = src[(size_t)(c0 + j) * 1024];     // coalesced along pl
      f16 h = (f16)v;
      h8[j] = h;
      l8[j] = (f16)((v - (float)h) * 4096.0f);    // scaled low limb, normal range
    }
    *(f16x8*)(zhi + n * CDIM + c0) = h8;
    *(f16x8*)(zlo + n * CDIM + c0) = l8;
  }
}

// ---------------- K0b: z_sq, bit-exact replication of numpy pairwise fp32 sum ----------------
__global__ void k_zsq(const float* __restrict__ z, float* __restrict__ zsq) {
#pragma clang fp contract(off)
  int n = blockIdx.x * 256 + threadIdx.x;
  int b = n >> 10, p = n & 1023;
  const float* src = z + (size_t)b * CDIM * 1024 + p;
  float half[2];
  for (int m = 0; m < 2; ++m) {
    float r[8];
#pragma unroll
    for (int j = 0; j < 8; ++j) r[j] = 0.0f;
    for (int i = 0; i < 16; ++i) {
#pragma unroll
      for (int j = 0; j < 8; ++j) {
        float v = src[(size_t)(m * 128 + i * 8 + j) * 1024];   // coalesced across lanes
        r[j] = r[j] + v * v;                                   // mul then add (no fma)
      }
    }
    half[m] = ((r[0] + r[1]) + (r[2] + r[3])) + ((r[4] + r[5]) + (r[6] + r[7]));
  }
  zsq[n] = half[0] + half[1];
}

// ---------------- K1: codebook -> chi/clo fp16 (scaled by 8192) ----------------
__global__ void k_cbsplit(const float* __restrict__ cb, f16* __restrict__ chi,
                          f16* __restrict__ clo) {
  int row  = blockIdx.x * 4 + (threadIdx.x >> 6);   // one wave per row
  int lane = threadIdx.x & 63;
  const float4 v = *(const float4*)(cb + (size_t)row * CDIM + lane * 4);
  float e0 = v.x * 8192.0f, e1 = v.y * 8192.0f, e2 = v.z * 8192.0f, e3 = v.w * 8192.0f;
  f16 h0 = (f16)e0, h1 = (f16)e1, h2 = (f16)e2, h3 = (f16)e3;
  f16x4 hi4 = {h0, h1, h2, h3};
  f16x4 lo4 = {(f16)((e0 - (float)h0) * 4096.0f), (f16)((e1 - (float)h1) * 4096.0f),
               (f16)((e2 - (float)h2) * 4096.0f), (f16)((e3 - (float)h3) * 4096.0f)};
  *(f16x4*)(chi + (size_t)row * CDIM + lane * 4) = hi4;
  *(f16x4*)(clo + (size_t)row * CDIM + lane * 4) = lo4;
}

// ---------------- K1b: e_sq, bit-exact numpy pairwise (thread per row) ----------------
__global__ void k_esq(const float* __restrict__ cb, float* __restrict__ esq) {
#pragma clang fp contract(off)
  int row = blockIdx.x * 256 + threadIdx.x;
  const float* src = cb + (size_t)row * CDIM;
  float half[2];
  for (int m = 0; m < 2; ++m) {
    float r[8];
#pragma unroll
    for (int j = 0; j < 8; ++j) r[j] = 0.0f;
    for (int i = 0; i < 16; ++i) {
      float4 v0 = *(const float4*)(src + m * 128 + i * 8);
      float4 v1 = *(const float4*)(src + m * 128 + i * 8 + 4);
      r[0] = r[0] + v0.x * v0.x;  r[1] = r[1] + v0.y * v0.y;
      r[2] = r[2] + v0.z * v0.z;  r[3] = r[3] + v0.w * v0.w;
      r[4] = r[4] + v1.x * v1.x;  r[5] = r[5] + v1.y * v1.y;
      r[6] = r[6] + v1.z * v1.z;  r[7] = r[7] + v1.w * v1.w;
    }
    half[m] = ((r[0] + r[1]) + (r[2] + r[3])) + ((r[4] + r[5]) + (r[6] + r[7]));
  }
  esq[row] = half[0] + half[1];
}

// ---------------- K2: fused score GEMM + argmin ----------------
// 2048 blocks; job = (kslice, ptile) claimed at runtime: kslice = this block's
// actual XCD id (so the 1 MB hi+lo codebook slice is L2-resident per XCD),
// ptile = per-slice ticket. Pigeonhole: a block that sees all 8 counters
// >= 256 implies all 2048 jobs were claimed by *other* blocks -- impossible
// with 2048 blocks each claiming <= 1. So the claim loop always succeeds
// within the first 8 distinct trials.
// A-tile 64px x 256c hi+lo in 64KB LDS (16B xor swizzle); wave tile 64x32/iter.
__launch_bounds__(256, 1)
__global__ void k_score(const f16* __restrict__ zhi, const f16* __restrict__ zlo,
                        const f16* __restrict__ chi, const f16* __restrict__ clo,
                        const float* __restrict__ esq, const float* __restrict__ zsq,
                        int* __restrict__ cnt,
                        unsigned long long* __restrict__ best) {
  extern __shared__ char smem[];
  f16* sAh = (f16*)smem;               // 32 KB
  f16* sAl = (f16*)(smem + 32768);     // 32 KB
  int t = threadIdx.x;
  int wave = t >> 6, lane = t & 63;
  int quad = lane >> 4, l15 = lane & 15;

  // ---- claim (kslice, ptile) aligned to the real XCD ----
  __shared__ int s_job[2];
  if (t == 0) {
    unsigned xcc;
    asm volatile("s_getreg_b32 %0, hwreg(HW_REG_XCC_ID)" : "=s"(xcc));
    int x = (int)(xcc & 7u);
    int pt = -1, ks = 0;
    for (int trial = 0; trial < 16 && pt < 0; ++trial) {
      int j = (x + trial) & 7;
      int tk = atomicAdd(&cnt[j], 1);
      if (tk < 256) { pt = tk; ks = j; }
    }
    if (pt < 0) pt = 0;                // unreachable (see proof above)
    s_job[0] = pt; s_job[1] = ks;
  }
  __syncthreads();
  int ptile  = s_job[0];
  int kslice = s_job[1];
  int p0 = ptile * 64;

  // ---- stage A-tile (hi & lo), xor-swizzled at 16B granularity ----
  {
    int r = t >> 2, seg = t & 3;
    const uint4* gh = (const uint4*)zhi + ((size_t)(p0 + r)) * 32;
    const uint4* gl = (const uint4*)zlo + ((size_t)(p0 + r)) * 32;
    uint4* sh = (uint4*)sAh + r * 32;
    uint4* sl = (uint4*)sAl + r * 32;
#pragma unroll
    for (int j = 0; j < 8; ++j) {
      int blk = seg * 8 + j;
      int sb = blk ^ (r & 7);
      sh[sb] = gh[blk];
      sl[sb] = gl[blk];
    }
  }

  // Z for my 16 pixel rows (C/D layout: row = quad*4 + reg)
  float Zr[16];
#pragma unroll
  for (int rt = 0; rt < 4; ++rt)
#pragma unroll
    for (int rr = 0; rr < 4; ++rr)
      Zr[rt * 4 + rr] = zsq[p0 + rt * 16 + quad * 4 + rr];

  __syncthreads();

  float bs[16];
  int   bi[16];
#pragma unroll
  for (int j = 0; j < 16; ++j) { bs[j] = 3.0e38f; bi[j] = 0; }

  const f32x4 vzero = {0.0f, 0.0f, 0.0f, 0.0f};

#pragma unroll 1
  for (int iter = 0; iter < 8; ++iter) {
    int kbase = kslice * 1024 + iter * 128 + wave * 32;
    f32x4 hh[4][2], mx[4][2];
#pragma unroll
    for (int rt = 0; rt < 4; ++rt)
#pragma unroll
      for (int kt = 0; kt < 2; ++kt) { hh[rt][kt] = vzero; mx[rt][kt] = vzero; }

#pragma unroll
    for (int cs = 0; cs < 8; ++cs) {
      int c0 = cs * 32 + quad * 8;
      f16x8 bh[2], bl[2], ah[4], al[4];
#pragma unroll
      for (int kt = 0; kt < 2; ++kt) {
        size_t off = ((size_t)(kbase + kt * 16 + l15)) * CDIM + c0;
        bh[kt] = *(const f16x8*)(chi + off);
        bl[kt] = *(const f16x8*)(clo + off);
      }
#pragma unroll
      for (int rt = 0; rt < 4; ++rt) {
        int px = rt * 16 + l15;
        int sb = (cs * 4 + quad) ^ (px & 7);
        int eo = px * 256 + sb * 8;          // f16 units
        ah[rt] = *(const f16x8*)(sAh + eo);
        al[rt] = *(const f16x8*)(sAl + eo);
      }
#pragma unroll
      for (int rt = 0; rt < 4; ++rt)
#pragma unroll
        for (int kt = 0; kt < 2; ++kt) {
          hh[rt][kt] = __builtin_amdgcn_mfma_f32_16x16x32_f16(ah[rt], bh[kt], hh[rt][kt], 0, 0, 0);
          mx[rt][kt] = __builtin_amdgcn_mfma_f32_16x16x32_f16(ah[rt], bl[kt], mx[rt][kt], 0, 0, 0);
          mx[rt][kt] = __builtin_amdgcn_mfma_f32_16x16x32_f16(al[rt], bh[kt], mx[rt][kt], 0, 0, 0);
        }
    }

    // epilogue: replicate ref's fp32 rounding: d = fl(fl(Z - 2c) + es)
    // 2c = hh/4096 (exact scale) + mx/2^24 (one fmaf rounding)
#pragma unroll
    for (int kt = 0; kt < 2; ++kt) {
      int k = kbase + kt * 16 + l15;
      float es = esq[k];
#pragma unroll
      for (int rt = 0; rt < 4; ++rt)
#pragma unroll
        for (int rr = 0; rr < 4; ++rr) {
          float v = hh[rt][kt][rr] * 2.44140625e-4f;                       // /4096, exact
          float w = fmaf(mx[rt][kt][rr], 5.9604644775390625e-8f, v);       // ~2*cross
          float d = (Zr[rt * 4 + rr] - w) + es;                            // two fp32 roundings
          int j = rt * 4 + rr;
          if (d < bs[j]) { bs[j] = d; bi[j] = k; }
        }
    }
  }

  // ---- reduce across the 16 lanes of each quad, then across waves ----
  __syncthreads();                          // A-tile dead; reuse LDS
  unsigned long long* red = (unsigned long long*)smem;   // 4 waves x 64 rows
#pragma unroll
  for (int j = 0; j < 16; ++j) {
    float s = bs[j]; int i_ = bi[j];
#pragma unroll
    for (int m = 1; m <= 8; m <<= 1) {
      float s2 = __shfl_xor(s, m);
      int   i2 = __shfl_xor(i_, m);
      if (s2 < s || (s2 == s && i2 < i_)) { s = s2; i_ = i2; }
    }
    if (l15 == 0) {
      int row = ((j >> 2) << 4) + (quad << 2) + (j & 3);   // rt*16 + quad*4 + rr
      unsigned u = __float_as_uint(s);
      u = (u & 0x80000000u) ? ~u : (u | 0x80000000u);      // order-preserving map
      red[wave * 64 + row] = ((unsigned long long)u << 32) | (unsigned)i_;
    }
  }
  __syncthreads();
  if (wave == 0) {
    unsigned long long m0 = red[lane];
    unsigned long long m1 = red[64 + lane];
    unsigned long long m2 = red[128 + lane];
    unsigned long long m3 = red[192 + lane];
    unsigned long long a = m0 < m1 ? m0 : m1;
    unsigned long long c = m2 < m3 ? m2 : m3;
    a = a < c ? a : c;
    atomicMin(&best[p0 + lane], a);
  }
}

// ---------------- K3: gather quantized, write codes, accumulate loss ----------------
__global__ void k_gather(const float* __restrict__ z, const float* __restrict__ cb,
                         const unsigned long long* __restrict__ best,
                         float* __restrict__ out_codes, float* __restrict__ out_q,
                         float* __restrict__ lossac) {
  int b  = blockIdx.x >> 4;
  int cg = blockIdx.x & 15;
  int t  = threadIdx.x;
  int idx[4];
#pragma unroll
  for (int pi = 0; pi < 4; ++pi) {
    int p = t + pi * 256;
    unsigned long long pk = best[b * 1024 + p];
    idx[pi] = (int)(unsigned)(pk & 0xffffffffu);
    if (cg == 0) out_codes[b * 1024 + p] = (float)idx[pi];
  }
  float lsum = 0.0f;
#pragma unroll
  for (int ci = 0; ci < 16; ++ci) {
    int c = cg * 16 + ci;
#pragma unroll
    for (int pi = 0; pi < 4; ++pi) {
      int p = t + pi * 256;
      float q  = cb[(size_t)idx[pi] * CDIM + c];
      size_t o = ((size_t)(b * CDIM + c)) * 1024 + p;
      float zv = z[o];
      float d  = q - zv;
      out_q[o] = zv + d;                 // straight-through: same op order as reference
      lsum = fmaf(d, d, lsum);
    }
  }
#pragma unroll
  for (int m = 32; m >= 1; m >>= 1) lsum += __shfl_xor(lsum, m);
  __shared__ float wsum[4];
  if ((t & 63) == 0) wsum[t >> 6] = lsum;
  __syncthreads();
  if (t == 0) atomicAdd(lossac, wsum[0] + wsum[1] + wsum[2] + wsum[3]);
}

// ---------------- K4: finalize loss scalar ----------------
__global__ void k_final(const float* __restrict__ lossac, float* __restrict__ out_loss) {
  if (threadIdx.x == 0) out_loss[0] = lossac[0] * (1.25f / 4194304.0f);
}

extern "C" void kernel_launch(void* const* d_in, const int* in_sizes, int n_in,
                              void* d_out, int out_size, void* d_ws, size_t ws_size,
                              hipStream_t stream) {
  (void)in_sizes; (void)n_in; (void)out_size; (void)ws_size;
  const float* z  = (const float*)d_in[0];
  const float* cb = (const float*)d_in[1];
  float* outf = (float*)d_out;

  char* ws = (char*)d_ws;
  f16*   chi  = (f16*)ws;                                   // 4 MB
  f16*   clo  = (f16*)(ws + (4 << 20));                     // 4 MB
  float* esq  = (float*)(ws + (8 << 20));                   // 32 KB
  unsigned long long* best = (unsigned long long*)(ws + (8 << 20) + 32768);  // 128 KB
  float* lossac = (float*)(ws + (8 << 20) + 32768 + 131072);                 // 4 B (pad 256)
  float* zsq    = (float*)(ws + (8 << 20) + 32768 + 131072 + 256);           // 64 KB
  int*   cnt    = (int*)  (ws + (8 << 20) + 32768 + 131072 + 256 + 65536);   // 32 B

  // scratch inside d_out's quantized region (overwritten by k_gather afterwards)
  f16* zhi = (f16*)(outf + 16384);                          // 8 MB
  f16* zlo = zhi + (size_t)NPIX * CDIM;                     // 8 MB

  hipMemsetAsync(best, 0xFF, (size_t)NPIX * 8, stream);
  hipMemsetAsync(lossac, 0, 4, stream);
  hipMemsetAsync(cnt, 0, 32, stream);

  k_zsplit <<<256,  256, 0,     stream>>>(z, zhi, zlo);
  k_zsq    <<<64,   256, 0,     stream>>>(z, zsq);
  k_cbsplit<<<2048, 256, 0,     stream>>>(cb, chi, clo);
  k_esq    <<<32,   256, 0,     stream>>>(cb, esq);
  k_score  <<<2048, 256, 65536, stream>>>(zhi, zlo, chi, clo, esq, zsq, cnt, best);
  k_gather <<<256,  256, 0,     stream>>>(z, cb, best, outf, outf + 16384, lossac);
  k_final  <<<1,    64,  0,     stream>>>(lossac, outf + 16384 + (size_t)NPIX * CDIM);
}